// Round 1
// baseline (66.075 us; speedup 1.0000x reference)
//
#include <hip/hip_runtime.h>

// ive(63, z) = exp(-z) * I_63(z) via the power series, summed in linear space
// relative to the peak term (analytic argmax), fixed 44+44 window, per-block
// LDS tables for lgamma-pair constants and reciprocal denominators.

constexpr int BLOCK = 256;
constexpr int EPT   = 4;    // elements per thread (float4 load/store)
constexpr int WIDTH = 44;   // series half-window; see analysis (max needed ~42)

__global__ __launch_bounds__(BLOCK) void ive63_kernel(const float* __restrict__ zin,
                                                      float* __restrict__ out,
                                                      int n) {
    // Per-block tables:
    //   c_lds[k]  = lgamma(k+1) + lgamma(k+64)              (log-scale constants)
    //   rc_lds[k] = 1 / ((k+1)*(k+64))                      (up-recurrence recip)
    __shared__ float c_lds[256];
    __shared__ float rc_lds[256];
    {
        const int k = threadIdx.x;
        const float kf = (float)k;
        c_lds[k]  = lgammaf(kf + 1.0f) + lgammaf(kf + 64.0f);
        rc_lds[k] = 1.0f / ((kf + 1.0f) * (kf + 64.0f));
    }
    __syncthreads();

    const int base = (blockIdx.x * BLOCK + threadIdx.x) * EPT;
    if (base >= n) return;

    float zz[EPT];
    if (base + EPT <= n) {
        const float4 v = *reinterpret_cast<const float4*>(zin + base);
        zz[0] = v.x; zz[1] = v.y; zz[2] = v.z; zz[3] = v.w;
    } else {
        #pragma unroll
        for (int e = 0; e < EPT; ++e) zz[e] = (base + e < n) ? zin[base + e] : 1.0f;
    }

    float rr[EPT];
    #pragma unroll
    for (int e = 0; e < EPT; ++e) {
        const float z = zz[e];
        const float L    = __logf(0.5f * z);       // log(z/2)
        const float q    = 0.25f * z * z;          // (z/2)^2
        const float qinv = 1.0f / q;

        // argmax of log-terms: k* = (sqrt(63^2 + z^2) - 65)/2, clamped
        int kc = (int)((sqrtf(fmaf(z, z, 3969.0f)) - 65.0f) * 0.5f);
        kc = kc < 0 ? 0 : (kc > 211 ? 211 : kc);   // keep kc+WIDTH-1 <= 254

        // log of peak term
        const float logt = fmaf((float)(63 + 2 * kc), L, -c_lds[kc]);

        // scaled sum around the peak: S = 1 + sum_up + sum_down
        // up:   t_{k+1}/t_k = q / ((k+1)(k+64)) = q * rc[k]
        // down: t_{k-1}/t_k = k(k+63) / q       (self-terminates at k=0)
        float u1 = 1.0f, u2 = 1.0f, S1 = 0.0f, S2 = 0.0f;
        float kd = (float)kc;
        const float* rcp = &rc_lds[kc];
        #pragma unroll 4
        for (int j = 0; j < WIDTH; ++j) {
            u1 *= q * rcp[j];
            S1 += u1;
            u2 *= (kd * (kd + 63.0f)) * qinv;
            S2 += u2;
            kd -= 1.0f;
        }
        const float S = 1.0f + S1 + S2;

        // ive = exp(log t_peak + log S - z); underflows to 0 exactly like ref
        rr[e] = __expf(logt + __logf(S) - z);
    }

    if (base + EPT <= n) {
        *reinterpret_cast<float4*>(out + base) = make_float4(rr[0], rr[1], rr[2], rr[3]);
    } else {
        #pragma unroll
        for (int e = 0; e < EPT; ++e) if (base + e < n) out[base + e] = rr[e];
    }
}

extern "C" void kernel_launch(void* const* d_in, const int* in_sizes, int n_in,
                              void* d_out, int out_size, void* d_ws, size_t ws_size,
                              hipStream_t stream) {
    const float* z = (const float*)d_in[0];
    float* o = (float*)d_out;
    const int n = in_sizes[0];
    const int grid = (n + BLOCK * EPT - 1) / (BLOCK * EPT);
    hipLaunchKernelGGL(ive63_kernel, dim3(grid), dim3(BLOCK), 0, stream, z, o, n);
}

// Round 3
// 61.824 us; speedup vs baseline: 1.0688x; 1.0688x over previous
//
#include <hip/hip_runtime.h>

// ive(63, z) = exp(-z) * I_63(z) via the power series, summed in linear space
// relative to the peak term t_{k*} (analytic argmax k* = (sqrt(63^2+z^2)-65)/2).
// Two multiplicative recurrence chains (up/down from the peak), fixed window
// WIDTH=28 each side. Truncation at worst case (z->200): edge term 2.6e-4 of
// peak, tail/S ~ 3e-5 relative -> <5e-11 absolute (output max ~1.5e-6).
// Down-chain factor k(k+63)/q self-terminates at k=0 (factor 0, no branch).
// Fixed trip count => zero divergence (lanes see i.i.d. z anyway).

constexpr int BLOCK = 256;
constexpr int EPT   = 4;    // elements per thread (float4 load/store)
constexpr int WIDTH = 28;   // per-side series half-window (see analysis)
constexpr int TBL   = 128;  // kc <= 72 for z<200, clamped to 95; 95+27 < 128

__global__ __launch_bounds__(BLOCK) void ive63_kernel(const float* __restrict__ zin,
                                                      float* __restrict__ out,
                                                      int n) {
    // Per-block tables:
    //   c_lds[k]  = lgamma(k+1) + lgamma(k+64)   (peak-term log constant)
    //   rc_lds[k] = 1 / ((k+1)*(k+64))           (up-recurrence reciprocal)
    __shared__ float c_lds[TBL];
    __shared__ float rc_lds[TBL];
    if (threadIdx.x < TBL) {
        const float kf = (float)threadIdx.x;
        c_lds[threadIdx.x]  = lgammaf(kf + 1.0f) + lgammaf(kf + 64.0f);
        rc_lds[threadIdx.x] = 1.0f / ((kf + 1.0f) * (kf + 64.0f));
    }
    __syncthreads();

    const int base = (blockIdx.x * BLOCK + threadIdx.x) * EPT;
    if (base >= n) return;

    float zz[EPT];
    if (base + EPT <= n) {
        const float4 v = *reinterpret_cast<const float4*>(zin + base);
        zz[0] = v.x; zz[1] = v.y; zz[2] = v.z; zz[3] = v.w;
    } else {
        #pragma unroll
        for (int e = 0; e < EPT; ++e) zz[e] = (base + e < n) ? zin[base + e] : 1.0f;
    }

    float rr[EPT];
    #pragma unroll
    for (int e = 0; e < EPT; ++e) {
        const float z = zz[e];
        const float L    = __logf(0.5f * z);       // log(z/2)
        const float q    = 0.25f * z * z;          // (z/2)^2
        const float qinv = 1.0f / q;

        // argmax of log-terms: k* = (sqrt(63^2 + z^2) - 65)/2, clamped
        int kc = (int)((sqrtf(fmaf(z, z, 3969.0f)) - 65.0f) * 0.5f);
        kc = kc < 0 ? 0 : (kc > 95 ? 95 : kc);     // keep kc+WIDTH-1 < TBL

        // log of peak term
        const float logt = fmaf((float)(63 + 2 * kc), L, -c_lds[kc]);

        // scaled sum around the peak: S = 1 + sum_up + sum_down
        // up:   t_{k+1}/t_k = q / ((k+1)(k+64)) = q * rc[k]
        // down: t_{k-1}/t_k = k(k+63) / q       (self-terminates at k=0)
        float u1 = 1.0f, u2 = 1.0f, S1 = 0.0f, S2 = 0.0f;
        float kd = (float)kc;
        const float* rcp = &rc_lds[kc];
        #pragma unroll
        for (int j = 0; j < WIDTH; ++j) {
            u1 *= q * rcp[j];
            S1 += u1;
            u2 *= (kd * (kd + 63.0f)) * qinv;
            S2 += u2;
            kd -= 1.0f;
        }
        const float S = 1.0f + S1 + S2;

        // ive = exp(log t_peak + log S - z); underflows to 0 exactly like ref
        rr[e] = __expf(logt + __logf(S) - z);
    }

    if (base + EPT <= n) {
        *reinterpret_cast<float4*>(out + base) = make_float4(rr[0], rr[1], rr[2], rr[3]);
    } else {
        #pragma unroll
        for (int e = 0; e < EPT; ++e) if (base + e < n) out[base + e] = rr[e];
    }
}

extern "C" void kernel_launch(void* const* d_in, const int* in_sizes, int n_in,
                              void* d_out, int out_size, void* d_ws, size_t ws_size,
                              hipStream_t stream) {
    const float* z = (const float*)d_in[0];
    float* o = (float*)d_out;
    const int n = in_sizes[0];
    const int grid = (n + BLOCK * EPT - 1) / (BLOCK * EPT);
    hipLaunchKernelGGL(ive63_kernel, dim3(grid), dim3(BLOCK), 0, stream, z, o, n);
}

// Round 11
// 55.466 us; speedup vs baseline: 1.1913x; 1.1146x over previous
//
#include <hip/hip_runtime.h>

// ive(63, z) = exp(-z) * I_63(z) via Olver's uniform large-order asymptotic
// expansion (A&S 9.7.7), valid uniformly in z for large order nu:
//   I_nu(nu*x) ~ e^{nu*eta} / (sqrt(2*pi*nu) * (1+x^2)^{1/4})
//                * (1 + u1(t)/nu + u2(t)/nu^2 + ...)
//   t = 1/sqrt(1+x^2),  eta = sqrt(1+x^2) + ln( x / (1 + sqrt(1+x^2)) )
//   u1(t) = (3t - 5t^3)/24,  u2(t) = (81t^2 - 462t^4 + 385t^6)/1152
// With nu=63 and z in [0.1, 200): t in (0.30, 1.0]; in the only region where
// the output is large enough for absolute error to matter (z near 200,
// output ~1.5e-6, t~0.30): u1/nu ~ 5e-4, u2/nu^2 ~ 8e-7, u3/nu^3 ~ 8e-10
// -- u3 is below f32 epsilon of the bracket (~1), so u0..u2 is f32-exact.
// Exponent-path f32 rounding ~1e-4 -> <= 2e-10 absolute at the output peak.
// Small z: exponent ~ -hundreds, exp underflows to 0 exactly like the
// reference's exp(logsumexp - z). No LDS, no loop, ~18 VALU + 5 trans/elem.

constexpr int BLOCK = 256;
constexpr int EPT   = 4;    // elements per thread (float4 load/store)

__global__ __launch_bounds__(BLOCK) void ive63_kernel(const float* __restrict__ zin,
                                                      float* __restrict__ out,
                                                      int n) {
    const int base = (blockIdx.x * BLOCK + threadIdx.x) * EPT;
    if (base >= n) return;

    float zz[EPT];
    if (base + EPT <= n) {
        const float4 v = *reinterpret_cast<const float4*>(zin + base);
        zz[0] = v.x; zz[1] = v.y; zz[2] = v.z; zz[3] = v.w;
    } else {
        #pragma unroll
        for (int e = 0; e < EPT; ++e) zz[e] = (base + e < n) ? zin[base + e] : 1.0f;
    }

    float rr[EPT];
    #pragma unroll
    for (int e = 0; e < EPT; ++e) {
        const float z  = zz[e];
        const float x  = z * (1.0f / 63.0f);
        const float x2 = x * x;
        const float s2 = 1.0f + x2;            // 1 + x^2
        const float t  = __frsqrt_rn(s2);      // (1+x^2)^{-1/2}
        const float s  = s2 * t;               // sqrt(1+x^2)

        // eta = s + ln(x) - ln(1+s);  exponent = nu*eta - z
        const float a    = s + __logf(x) - __logf(1.0f + s);
        const float expo = fmaf(63.0f, a, -z);

        // prefactor: 1/sqrt(2*pi*63) * (1+x^2)^{-1/4} = C0 * sqrt(t)
        const float pref = 0.05026201f * __fsqrt_rn(t);

        // bracket: 1 + u1/nu + u2/nu^2
        const float t2 = t * t;
        const float p1 = t * fmaf(-5.0f, t2, 3.0f) * (1.0f / 1512.0f);       // u1/63
        const float q2 = fmaf(fmaf(385.0f, t2, -462.0f), t2, 81.0f);         // 385t^4-462t^2+81
        const float p2 = t2 * q2 * (1.0f / 4572288.0f);                      // u2/63^2
        const float S  = 1.0f + p1 + p2;

        rr[e] = __expf(expo) * pref * S;
    }

    if (base + EPT <= n) {
        *reinterpret_cast<float4*>(out + base) = make_float4(rr[0], rr[1], rr[2], rr[3]);
    } else {
        #pragma unroll
        for (int e = 0; e < EPT; ++e) if (base + e < n) out[base + e] = rr[e];
    }
}

extern "C" void kernel_launch(void* const* d_in, const int* in_sizes, int n_in,
                              void* d_out, int out_size, void* d_ws, size_t ws_size,
                              hipStream_t stream) {
    const float* z = (const float*)d_in[0];
    float* o = (float*)d_out;
    const int n = in_sizes[0];
    const int grid = (n + BLOCK * EPT - 1) / (BLOCK * EPT);
    hipLaunchKernelGGL(ive63_kernel, dim3(grid), dim3(BLOCK), 0, stream, z, o, n);
}